// Round 2
// baseline (2482.069 us; speedup 1.0000x reference)
//
#include <hip/hip_runtime.h>
#include <hip/hip_bf16.h>

// APPNP: h0 = MLP(x); 10x { h = 0.9 * A_hat h + 0.1 * h0 }; log_softmax.
// A_hat = D^-1/2 (A + I) D^-1/2 over col-targets (PyG gcn_norm).
//
// R1 changes (NaN post-mortem -> ws-overflow hypothesis):
//  - scratch diet: ~104MB -> ~40MB (tiered h dtype, no snorm, d_out = pong buffer)
//  - all edge-derived indices clamped to [0,N) (no OOB scatter possible)
//  - hardened on-device dtype sniffing (1024 samples)

#define WPB 4   // waves (nodes) per 256-thread block

// ---- dtype helpers -------------------------------------------------------
__device__ __forceinline__ float loadF(const void* p, size_t i, int bf) {
  if (bf) return __bfloat162float(((const __hip_bfloat16*)p)[i]);
  return ((const float*)p)[i];
}
__device__ __forceinline__ float loadH(const void* p, size_t i, int dt) {
  if (dt) return __bfloat162float(((const __hip_bfloat16*)p)[i]);
  return ((const float*)p)[i];
}
__device__ __forceinline__ void storeH(void* p, size_t i, int dt, float v) {
  if (dt) ((__hip_bfloat16*)p)[i] = __float2bfloat16(v);
  else ((float*)p)[i] = v;
}

// flags[0]: 1 if float tensors are bf16, else fp32. flags[1]: 1 if idx int64.
__global__ void detect_k(const void* x, const int* ei, int* flags) {
  if (blockIdx.x == 0 && threadIdx.x == 0) {
    const int S = 1024;
    int sane = 0;
    const __hip_bfloat16* xb = (const __hip_bfloat16*)x;
    for (int i = 0; i < S; i++) {
      float v = __bfloat162float(xb[i]);
      if (v == v && fabsf(v) < 64.f) sane++;
    }
    flags[0] = (sane >= S - S / 32) ? 1 : 0;   // >=992/1024: true bf16 is 1024/1024
    int zer = 0;
    for (int e = 0; e < S; e++) if (ei[2 * e + 1] == 0) zer++;
    flags[1] = (zer >= S - S / 8) ? 1 : 0;     // int64 high words ~all zero
  }
}

__device__ __forceinline__ int clampN(int v, int N) {
  v = v < 0 ? 0 : v;
  return v >= N ? N - 1 : v;
}

__global__ void count_k(const int* __restrict__ ei, int E, int N,
                        int* __restrict__ counts, const int* __restrict__ flags) {
  int e = blockIdx.x * blockDim.x + threadIdx.x;
  if (e >= E) return;
  int wide = flags[1];
  long le = e;
  int c = wide ? ei[2 * ((long)E + le)] : ei[(long)E + le];
  c = clampN(c, N);
  atomicAdd(&counts[c], 1);
}

// Single block: chunked serial scan + Hillis-Steele over 1024 partials.
// Writes colptr, turns counts into the scatter cursor, emits dinv = rsqrt(1+deg).
__global__ void scan_k(int* __restrict__ counts, int N,
                       int* __restrict__ colptr, float* __restrict__ dinv) {
  __shared__ int sums[1024];
  int t = threadIdx.x;
  int chunk = (N + 1023) >> 10;
  int lo = t * chunk, hi = min(lo + chunk, N);
  int s = 0;
  for (int i = lo; i < hi; i++) s += counts[i];
  sums[t] = s;
  __syncthreads();
  for (int off = 1; off < 1024; off <<= 1) {
    int v = (t >= off) ? sums[t - off] : 0;
    __syncthreads();
    sums[t] += v;
    __syncthreads();
  }
  int base = (t == 0) ? 0 : sums[t - 1];
  for (int i = lo; i < hi; i++) {
    int c = counts[i];
    colptr[i] = base;
    counts[i] = base;                       // counts becomes the fill cursor
    dinv[i] = rsqrtf(1.0f + (float)c);      // self-loop included
    base += c;
  }
  if (t == 1023) colptr[N] = base;          // == E
}

__global__ void fill_k(const int* __restrict__ ei, int E, int N,
                       int* __restrict__ cursor, int* __restrict__ srow,
                       const int* __restrict__ flags) {
  int e = blockIdx.x * blockDim.x + threadIdx.x;
  if (e >= E) return;
  int wide = flags[1];
  long le = e;
  int r = wide ? ei[2 * le] : ei[le];
  int c = wide ? ei[2 * ((long)E + le)] : ei[(long)E + le];
  r = clampN(r, N); c = clampN(c, N);
  int slot = atomicAdd(&cursor[c], 1);
  srow[slot] = r;
}

// h1 = relu(x@W1+b1) [16]; h2 = h1@W2+b2 [64]. One wave per node.
// W1 staged in LDS, 16 floats/row, chunk-rotated by (row>>1)&3 (conflict-free float4).
__global__ __launch_bounds__(256) void mlp_k(
    const void* __restrict__ x, const void* __restrict__ W1,
    const void* __restrict__ b1, const void* __restrict__ W2,
    const void* __restrict__ b2, const int* __restrict__ flags,
    void* __restrict__ h0, void* __restrict__ ping, int hdt, int N) {
  __shared__ __align__(16) float W1s[512 * 16];
  __shared__ float W2s[16 * 64];
  __shared__ float b1s[16];
  __shared__ float b2s[64];
  __shared__ float h1s[WPB][16];

  const int tid = threadIdx.x;
  const int fm = flags[0];

  for (int idx = tid; idx < 512 * 16; idx += 256) {
    int r = idx >> 4, j = idx & 15;
    int phys = r * 16 + ((((j >> 2) + (r >> 1)) & 3) << 2) + (j & 3);
    W1s[phys] = loadF(W1, idx, fm);
  }
  for (int idx = tid; idx < 16 * 64; idx += 256) W2s[idx] = loadF(W2, idx, fm);
  if (tid < 16) b1s[tid] = loadF(b1, tid, fm);
  else if (tid >= 64 && tid < 128) b2s[tid - 64] = loadF(b2, tid - 64, fm);
  __syncthreads();

  const int lane = tid & 63;
  const int wv = tid >> 6;
  const int node = blockIdx.x * WPB + wv;
  if (node >= N) return;

  float p[16];
#pragma unroll
  for (int j = 0; j < 16; j++) p[j] = 0.f;

  const size_t xbase = (size_t)node * 512;
#pragma unroll
  for (int k = 0; k < 8; k++) {
    const int r = k * 64 + lane;
    const float xv = loadF(x, xbase + r, fm);
    const int rot = (r >> 1) & 3;
#pragma unroll
    for (int c = 0; c < 4; c++) {
      const float4 w = *reinterpret_cast<const float4*>(
          &W1s[r * 16 + (((c + rot) & 3) << 2)]);
      p[4 * c + 0] += xv * w.x;
      p[4 * c + 1] += xv * w.y;
      p[4 * c + 2] += xv * w.z;
      p[4 * c + 3] += xv * w.w;
    }
  }

  // Folding cross-lane reduction: lane ends holding channel (lane>>2)&15.
#pragma unroll
  for (int j = 0; j < 8; j++) {
    float send = (lane & 32) ? p[j] : p[j + 8];
    float recv = __shfl_xor(send, 32, 64);
    p[j] = ((lane & 32) ? p[j + 8] : p[j]) + recv;
  }
#pragma unroll
  for (int j = 0; j < 4; j++) {
    float send = (lane & 16) ? p[j] : p[j + 4];
    float recv = __shfl_xor(send, 16, 64);
    p[j] = ((lane & 16) ? p[j + 4] : p[j]) + recv;
  }
#pragma unroll
  for (int j = 0; j < 2; j++) {
    float send = (lane & 8) ? p[j] : p[j + 2];
    float recv = __shfl_xor(send, 8, 64);
    p[j] = ((lane & 8) ? p[j + 2] : p[j]) + recv;
  }
  {
    float send = (lane & 4) ? p[0] : p[1];
    float recv = __shfl_xor(send, 4, 64);
    p[0] = ((lane & 4) ? p[1] : p[0]) + recv;
  }
  p[0] += __shfl_xor(p[0], 2, 64);
  p[0] += __shfl_xor(p[0], 1, 64);

  const int c = (lane >> 2) & 15;
  if ((lane & 3) == 0) h1s[wv][c] = fmaxf(p[0] + b1s[c], 0.f);

  float h2 = b2s[lane];
#pragma unroll
  for (int j = 0; j < 16; j++) h2 += h1s[wv][j] * W2s[j * 64 + lane];
  const size_t o = (size_t)node * 64 + lane;
  storeH(h0, o, hdt, h2);
  storeH(ping, o, hdt, h2);
}

// One wave per target node; lane = channel. CSR gather, norm recomputed from dinv.
// dt codes: 0 = fp32, 1 = bf16, 2 = use flags[0] (d_out's dtype).
__global__ __launch_bounds__(256) void gather_k(
    const void* __restrict__ hcur, int cur_dt,
    const void* __restrict__ h0, int h0_dt,
    const int* __restrict__ colptr, const int* __restrict__ srow,
    const float* __restrict__ dinv,
    void* __restrict__ hnext, int nxt_dt,
    const int* __restrict__ flags, int N) {
  const int gw = (int)((blockIdx.x * (size_t)blockDim.x + threadIdx.x) >> 6);
  if (gw >= N) return;
  const int lane = threadIdx.x & 63;
  const int f0 = flags[0];
  const int cdt = (cur_dt == 2) ? f0 : cur_dt;
  const int ndt = (nxt_dt == 2) ? f0 : nxt_dt;
  int beg = __builtin_amdgcn_readfirstlane(colptr[gw]);
  int end = __builtin_amdgcn_readfirstlane(colptr[gw + 1]);
  const float di = dinv[gw];
  const size_t base = (size_t)gw * 64 + lane;
  float acc = di * di * loadH(hcur, base, cdt);    // self-loop term
  int t = beg;
  for (; t + 4 <= end; t += 4) {
    int j0 = clampN(srow[t + 0], N), j1 = clampN(srow[t + 1], N);
    int j2 = clampN(srow[t + 2], N), j3 = clampN(srow[t + 3], N);
    float n0 = dinv[j0] * di, n1 = dinv[j1] * di;
    float n2 = dinv[j2] * di, n3 = dinv[j3] * di;
    float v0 = loadH(hcur, (size_t)j0 * 64 + lane, cdt);
    float v1 = loadH(hcur, (size_t)j1 * 64 + lane, cdt);
    float v2 = loadH(hcur, (size_t)j2 * 64 + lane, cdt);
    float v3 = loadH(hcur, (size_t)j3 * 64 + lane, cdt);
    acc += n0 * v0; acc += n1 * v1; acc += n2 * v2; acc += n3 * v3;
  }
  for (; t < end; ++t) {
    int j = clampN(srow[t], N);
    acc += dinv[j] * di * loadH(hcur, (size_t)j * 64 + lane, cdt);
  }
  storeH(hnext, base, ndt, 0.9f * acc + 0.1f * loadH(h0, base, h0_dt));
}

__global__ __launch_bounds__(256) void lsm_k(const void* __restrict__ hin, int hdt,
                                             void* __restrict__ out,
                                             const int* __restrict__ flags, int N) {
  const int gw = (int)((blockIdx.x * (size_t)blockDim.x + threadIdx.x) >> 6);
  if (gw >= N) return;
  const int lane = threadIdx.x & 63;
  const size_t o = (size_t)gw * 64 + lane;
  float v = loadH(hin, o, hdt);
  float m = v;
#pragma unroll
  for (int off = 32; off; off >>= 1) m = fmaxf(m, __shfl_xor(m, off, 64));
  float e = __expf(v - m);
  float s = e;
#pragma unroll
  for (int off = 32; off; off >>= 1) s += __shfl_xor(s, off, 64);
  float r = v - m - __logf(s);
  if (flags[0]) ((__hip_bfloat16*)out)[o] = __float2bfloat16(r);
  else ((float*)out)[o] = r;
}

extern "C" void kernel_launch(void* const* d_in, const int* in_sizes, int n_in,
                              void* d_out, int out_size, void* d_ws, size_t ws_size,
                              hipStream_t stream) {
  (void)n_in; (void)out_size;
  const void* x  = d_in[0];
  const void* W1 = d_in[1];
  const void* b1 = d_in[2];
  const void* W2 = d_in[3];
  const void* b2 = d_in[4];
  const int* ei  = (const int*)d_in[5];

  const int N = in_sizes[0] / 512;
  const int E = in_sizes[5] / 2;

  // Tier: store h0/ping as fp32 if workspace allows, else bf16.
  const size_t fixed = (size_t)E * 4 + (size_t)N * 4 * 2 + ((size_t)N + 1) * 4 + 4096;
  const size_t need_f32 = 2 * ((size_t)N * 64 * 4) + fixed + (1u << 20);
  const int tier_dt = (ws_size >= need_f32) ? 0 : 1;   // 0=fp32, 1=bf16
  const size_t hbytes = (size_t)N * 64 * (tier_dt ? 2 : 4);

  char* w = (char*)d_ws;
  size_t off = 0;
  auto alloc = [&](size_t bytes) -> void* {
    void* p = w + off;
    off += (bytes + 255) & ~(size_t)255;
    return p;
  };
  void*  h0     = alloc(hbytes);
  void*  ping   = alloc(hbytes);
  int*   srow   = (int*)alloc((size_t)E * 4);
  int*   counts = (int*)alloc((size_t)N * 4);        // becomes cursor after scan
  int*   colptr = (int*)alloc(((size_t)N + 1) * 4);
  float* dinv   = (float*)alloc((size_t)N * 4);
  int*   flags  = (int*)alloc(256);
  void*  pong   = d_out;                             // dtype = flags[0] at runtime

  hipMemsetAsync(counts, 0, (size_t)N * 4, stream);
  detect_k<<<1, 64, 0, stream>>>(x, ei, flags);
  count_k<<<(E + 255) / 256, 256, 0, stream>>>(ei, E, N, counts, flags);
  scan_k<<<1, 1024, 0, stream>>>(counts, N, colptr, dinv);
  fill_k<<<(E + 255) / 256, 256, 0, stream>>>(ei, E, N, counts, srow, flags);
  mlp_k<<<(N + WPB - 1) / WPB, 256, 0, stream>>>(x, W1, b1, W2, b2, flags,
                                                 h0, ping, tier_dt, N);

  const int gblocks = (N + WPB - 1) / WPB;
  for (int it = 0; it < 10; ++it) {
    if ((it & 1) == 0)
      gather_k<<<gblocks, 256, 0, stream>>>(ping, tier_dt, h0, tier_dt, colptr,
                                            srow, dinv, pong, 2, flags, N);
    else
      gather_k<<<gblocks, 256, 0, stream>>>(pong, 2, h0, tier_dt, colptr,
                                            srow, dinv, ping, tier_dt, flags, N);
  }
  // it9 wrote ping -> final h lives in ping
  lsm_k<<<gblocks, 256, 0, stream>>>(ping, tier_dt, d_out, flags, N);
}

// Round 3
// 1718.006 us; speedup vs baseline: 1.4447x; 1.4447x over previous
//
#include <hip/hip_runtime.h>
#include <hip/hip_bf16.h>

// APPNP: h0 = MLP(x); 10x { h = 0.9 * A_hat h + 0.1 * h0 }; log_softmax.
// A_hat = D^-1/2 (A + I) D^-1/2 over col-targets (PyG gcn_norm).
//
// R2: inputs confirmed bf16 (FETCH=100MB for x), ws large (tier was fp32).
//  - gather_k: octet-per-edge layout, uint4 (8 bf16 ch) per lane -> one wave
//    instr fetches 8 full 128B rows; h stored bf16 (halves L2/L3 traffic)
//  - mlp_k: 16x16x32 bf16 MFMA over K=512 (16 steps), W1 pre-swizzled in LDS
//  - detect_k parallelized; fp32 fallback = per-load wave-uniform branches

typedef unsigned short u16;
typedef __attribute__((ext_vector_type(8))) short short8;
typedef __attribute__((ext_vector_type(4))) float f32x4;

#define WPB 4   // waves per 256-thread block

// ---- helpers -------------------------------------------------------------
__device__ __forceinline__ float loadF(const void* p, size_t i, int bf) {
  if (bf) return __bfloat162float(((const __hip_bfloat16*)p)[i]);
  return ((const float*)p)[i];
}
__device__ __forceinline__ float blo(unsigned u) {
  return __uint_as_float(u << 16);
}
__device__ __forceinline__ float bhi(unsigned u) {
  return __uint_as_float(u & 0xffff0000u);
}
__device__ __forceinline__ u16 f2b(float v) {
  __hip_bfloat16 b = __float2bfloat16(v);
  return *reinterpret_cast<u16*>(&b);
}
__device__ __forceinline__ unsigned pk2(float lo, float hi) {
  return (unsigned)f2b(lo) | ((unsigned)f2b(hi) << 16);
}
__device__ __forceinline__ int clampN(int v, int N) {
  v = v < 0 ? 0 : v;
  return v >= N ? N - 1 : v;
}

// flags[0]: 1 if float tensors bf16; flags[1]: 1 if edge_index int64.
__global__ void detect_k(const void* x, const int* ei, int* flags) {
  __shared__ int red[2];
  const int tid = threadIdx.x;              // 1024 threads
  if (tid < 2) red[tid] = 0;
  __syncthreads();
  const __hip_bfloat16* xb = (const __hip_bfloat16*)x;
  float v = __bfloat162float(xb[tid]);
  int sane = (v == v && fabsf(v) < 64.f) ? 1 : 0;
  int zer = (ei[2 * tid + 1] == 0) ? 1 : 0;
  atomicAdd(&red[0], sane);
  atomicAdd(&red[1], zer);
  __syncthreads();
  if (tid == 0) {
    flags[0] = (red[0] >= 1024 - 32) ? 1 : 0;   // true bf16: 1024/1024
    flags[1] = (red[1] >= 1024 - 128) ? 1 : 0;  // int64 high words ~all zero
  }
}

__global__ void count_k(const int* __restrict__ ei, int E, int N,
                        int* __restrict__ counts, const int* __restrict__ flags) {
  int e = blockIdx.x * blockDim.x + threadIdx.x;
  if (e >= E) return;
  int wide = flags[1];
  long le = e;
  int c = wide ? ei[2 * ((long)E + le)] : ei[(long)E + le];
  atomicAdd(&counts[clampN(c, N)], 1);
}

// Single block scan: colptr, cursor (in counts), dinv = rsqrt(1+deg).
__global__ void scan_k(int* __restrict__ counts, int N,
                       int* __restrict__ colptr, float* __restrict__ dinv) {
  __shared__ int sums[1024];
  int t = threadIdx.x;
  int chunk = (N + 1023) >> 10;
  int lo = t * chunk, hi = min(lo + chunk, N);
  int s = 0;
  for (int i = lo; i < hi; i++) s += counts[i];
  sums[t] = s;
  __syncthreads();
  for (int off = 1; off < 1024; off <<= 1) {
    int v = (t >= off) ? sums[t - off] : 0;
    __syncthreads();
    sums[t] += v;
    __syncthreads();
  }
  int base = (t == 0) ? 0 : sums[t - 1];
  for (int i = lo; i < hi; i++) {
    int c = counts[i];
    colptr[i] = base;
    counts[i] = base;                       // becomes fill cursor
    dinv[i] = rsqrtf(1.0f + (float)c);      // self-loop included
    base += c;
  }
  if (t == 1023) colptr[N] = base;
}

__global__ void fill_k(const int* __restrict__ ei, int E, int N,
                       int* __restrict__ cursor, int* __restrict__ srow,
                       const int* __restrict__ flags) {
  int e = blockIdx.x * blockDim.x + threadIdx.x;
  if (e >= E) return;
  int wide = flags[1];
  long le = e;
  int r = wide ? ei[2 * le] : ei[le];
  int c = wide ? ei[2 * ((long)E + le)] : ei[(long)E + le];
  int slot = atomicAdd(&cursor[clampN(c, N)], 1);
  srow[slot] = clampN(r, N);
}

// MLP via MFMA: one wave per 16-node tile. Layer1: [16x512]@[512x16] in 16
// v_mfma_f32_16x16x32_bf16 steps. Layer2: [16x16]@[16x64] as VALU from LDS.
// A-frag: A[m=lane&15][k=quad*8+j]; B-frag: B[k=quad*8+j][n=lane&15];
// C: row(node)=quad*4+reg, col(ch)=lane&15.
__global__ __launch_bounds__(256) void mlp_k(
    const void* __restrict__ x, const void* __restrict__ W1,
    const void* __restrict__ b1, const void* __restrict__ W2,
    const void* __restrict__ b2, const int* __restrict__ flags,
    u16* __restrict__ h0, u16* __restrict__ ping, int N) {
  __shared__ __align__(16) short Blds[8192];   // [kstep][lane][j] bf16
  __shared__ float W2s[16 * 64];
  __shared__ float b1s[16];
  __shared__ float b2s[64];
  __shared__ float h1s[WPB][16][17];           // +1 pad

  const int tid = threadIdx.x;
  const int f0 = flags[0];

  for (int idx = tid; idx < 8192; idx += 256) {
    int ks = idx >> 9, ln = (idx >> 3) & 63, j = idx & 7;
    int k = ks * 32 + ((ln >> 4) << 3) + j;
    int n = ln & 15;
    float w = loadF(W1, (size_t)k * 16 + n, f0);
    Blds[idx] = (short)f2b(w);
  }
  for (int idx = tid; idx < 1024; idx += 256) W2s[idx] = loadF(W2, idx, f0);
  if (tid < 16) b1s[tid] = loadF(b1, tid, f0);
  else if (tid >= 64 && tid < 128) b2s[tid - 64] = loadF(b2, tid - 64, f0);
  __syncthreads();

  const int lane = tid & 63;
  const int wv = tid >> 6;
  const int tile = (blockIdx.x * WPB + wv) * 16;
  if (tile >= N) return;

  const int m = lane & 15;        // node-in-tile for A rows / channel for C
  const int quad = lane >> 4;
  const int row = min(tile + m, N - 1);
  const size_t rowbase = (size_t)row * 512 + (quad << 3);

  f32x4 acc = {0.f, 0.f, 0.f, 0.f};
#pragma unroll
  for (int ks = 0; ks < 16; ks++) {
    short8 a;
    if (f0) {
      a = *reinterpret_cast<const short8*>((const u16*)x + rowbase + ks * 32);
    } else {
      const float* xf = (const float*)x + rowbase + ks * 32;
      const float4 lo = *reinterpret_cast<const float4*>(xf);
      const float4 hi = *reinterpret_cast<const float4*>(xf + 4);
      a[0] = (short)f2b(lo.x); a[1] = (short)f2b(lo.y);
      a[2] = (short)f2b(lo.z); a[3] = (short)f2b(lo.w);
      a[4] = (short)f2b(hi.x); a[5] = (short)f2b(hi.y);
      a[6] = (short)f2b(hi.z); a[7] = (short)f2b(hi.w);
    }
    const short8 bf = *reinterpret_cast<const short8*>(&Blds[(ks * 64 + lane) * 8]);
    acc = __builtin_amdgcn_mfma_f32_16x16x32_bf16(a, bf, acc, 0, 0, 0);
  }

  // relu(+bias) -> LDS h1 tile. lane holds nodes quad*4+r, channel m.
#pragma unroll
  for (int r = 0; r < 4; r++)
    h1s[wv][quad * 4 + r][m] = fmaxf(acc[r] + b1s[m], 0.f);
  // same-wave LDS RAW: compiler inserts lgkmcnt wait; no barrier needed.

  // Layer 2: lane = output channel; 16 nodes serial.
  for (int mm = 0; mm < 16; mm++) {
    const int node = tile + mm;
    if (node >= N) break;
    float hh = b2s[lane];
#pragma unroll
    for (int j = 0; j < 16; j++) hh += h1s[wv][mm][j] * W2s[(j << 6) + lane];
    const u16 u = f2b(hh);
    const size_t o = (size_t)node * 64 + lane;
    h0[o] = u;
    ping[o] = u;
  }
}

// One wave per target node. Octet o=lane>>3 handles edges beg+o, beg+o+8,...;
// lane loads uint4 = 8 bf16 channels (s*8..s*8+7) -> one wave instruction
// fetches 8 complete 128B rows. Cross-octet combine via 3 shfl_xor per acc.
__global__ __launch_bounds__(256) void gather_k(
    const u16* __restrict__ hcur, const u16* __restrict__ h0,
    const int* __restrict__ colptr, const int* __restrict__ srow,
    const float* __restrict__ dinv, u16* __restrict__ hnext, int N) {
  const int gw = (int)((blockIdx.x * 256u + threadIdx.x) >> 6);
  if (gw >= N) return;
  const int lane = threadIdx.x & 63;
  const int o = lane >> 3, s = lane & 7;
  const int soff = s << 3;
  const int beg = __builtin_amdgcn_readfirstlane(colptr[gw]);
  const int end = __builtin_amdgcn_readfirstlane(colptr[gw + 1]);
  const float di = dinv[gw];

  float a0 = 0.f, a1 = 0.f, a2 = 0.f, a3 = 0.f;
  float a4 = 0.f, a5 = 0.f, a6 = 0.f, a7 = 0.f;
  for (int t = beg + o; t < end; t += 8) {
    const int j = srow[t];
    const float nj = dinv[j] * di;
    const uint4 u = *reinterpret_cast<const uint4*>(hcur + (((size_t)j) << 6) + soff);
    a0 = fmaf(nj, blo(u.x), a0); a1 = fmaf(nj, bhi(u.x), a1);
    a2 = fmaf(nj, blo(u.y), a2); a3 = fmaf(nj, bhi(u.y), a3);
    a4 = fmaf(nj, blo(u.z), a4); a5 = fmaf(nj, bhi(u.z), a5);
    a6 = fmaf(nj, blo(u.w), a6); a7 = fmaf(nj, bhi(u.w), a7);
  }
#pragma unroll
  for (int d = 8; d < 64; d <<= 1) {
    a0 += __shfl_xor(a0, d, 64); a1 += __shfl_xor(a1, d, 64);
    a2 += __shfl_xor(a2, d, 64); a3 += __shfl_xor(a3, d, 64);
    a4 += __shfl_xor(a4, d, 64); a5 += __shfl_xor(a5, d, 64);
    a6 += __shfl_xor(a6, d, 64); a7 += __shfl_xor(a7, d, 64);
  }

  const size_t base = (((size_t)gw) << 6) + soff;
  const uint4 hs = *reinterpret_cast<const uint4*>(hcur + base);
  const uint4 hz = *reinterpret_cast<const uint4*>(h0 + base);
  const float dd = di * di;
  const float r0 = 0.9f * (a0 + dd * blo(hs.x)) + 0.1f * blo(hz.x);
  const float r1 = 0.9f * (a1 + dd * bhi(hs.x)) + 0.1f * bhi(hz.x);
  const float r2 = 0.9f * (a2 + dd * blo(hs.y)) + 0.1f * blo(hz.y);
  const float r3 = 0.9f * (a3 + dd * bhi(hs.y)) + 0.1f * bhi(hz.y);
  const float r4 = 0.9f * (a4 + dd * blo(hs.z)) + 0.1f * blo(hz.z);
  const float r5 = 0.9f * (a5 + dd * bhi(hs.z)) + 0.1f * bhi(hz.z);
  const float r6 = 0.9f * (a6 + dd * blo(hs.w)) + 0.1f * blo(hz.w);
  const float r7 = 0.9f * (a7 + dd * bhi(hs.w)) + 0.1f * bhi(hz.w);
  if (o == 0) {
    uint4 pv;
    pv.x = pk2(r0, r1); pv.y = pk2(r2, r3);
    pv.z = pk2(r4, r5); pv.w = pk2(r6, r7);
    *reinterpret_cast<uint4*>(hnext + base) = pv;
  }
}

__global__ __launch_bounds__(256) void lsm_k(const u16* __restrict__ hin,
                                             void* __restrict__ out,
                                             const int* __restrict__ flags, int N) {
  const int gw = (int)((blockIdx.x * 256u + threadIdx.x) >> 6);
  if (gw >= N) return;
  const int lane = threadIdx.x & 63;
  const size_t o = (((size_t)gw) << 6) + lane;
  const float v = __bfloat162float(*reinterpret_cast<const __hip_bfloat16*>(&hin[o]));
  float m = v;
#pragma unroll
  for (int off = 32; off; off >>= 1) m = fmaxf(m, __shfl_xor(m, off, 64));
  float e = __expf(v - m);
  float ssum = e;
#pragma unroll
  for (int off = 32; off; off >>= 1) ssum += __shfl_xor(ssum, off, 64);
  const float r = v - m - __logf(ssum);
  if (flags[0]) ((__hip_bfloat16*)out)[o] = __float2bfloat16(r);
  else ((float*)out)[o] = r;
}

extern "C" void kernel_launch(void* const* d_in, const int* in_sizes, int n_in,
                              void* d_out, int out_size, void* d_ws, size_t ws_size,
                              hipStream_t stream) {
  (void)n_in; (void)out_size; (void)ws_size;
  const void* x  = d_in[0];
  const void* W1 = d_in[1];
  const void* b1 = d_in[2];
  const void* W2 = d_in[3];
  const void* b2 = d_in[4];
  const int* ei  = (const int*)d_in[5];

  const int N = in_sizes[0] / 512;
  const int E = in_sizes[5] / 2;

  char* w = (char*)d_ws;
  size_t off = 0;
  auto alloc = [&](size_t bytes) -> void* {
    void* p = w + off;
    off += (bytes + 255) & ~(size_t)255;
    return p;
  };
  u16*   h0     = (u16*)alloc((size_t)N * 64 * 2);
  u16*   ping   = (u16*)alloc((size_t)N * 64 * 2);
  int*   srow   = (int*)alloc((size_t)E * 4);
  int*   counts = (int*)alloc((size_t)N * 4);        // becomes cursor
  int*   colptr = (int*)alloc(((size_t)N + 1) * 4);
  float* dinv   = (float*)alloc((size_t)N * 4);
  int*   flags  = (int*)alloc(256);
  u16*   pong   = (u16*)d_out;   // intermediate bf16 storage; final write below

  hipMemsetAsync(counts, 0, (size_t)N * 4, stream);
  detect_k<<<1, 1024, 0, stream>>>(x, ei, flags);
  count_k<<<(E + 255) / 256, 256, 0, stream>>>(ei, E, N, counts, flags);
  scan_k<<<1, 1024, 0, stream>>>(counts, N, colptr, dinv);
  fill_k<<<(E + 255) / 256, 256, 0, stream>>>(ei, E, N, counts, srow, flags);
  mlp_k<<<(N + 63) / 64, 256, 0, stream>>>(x, W1, b1, W2, b2, flags, h0, ping, N);

  const int gblocks = (N + WPB - 1) / WPB;
  for (int it = 0; it < 10; ++it) {
    if ((it & 1) == 0)
      gather_k<<<gblocks, 256, 0, stream>>>(ping, h0, colptr, srow, dinv, pong, N);
    else
      gather_k<<<gblocks, 256, 0, stream>>>(pong, h0, colptr, srow, dinv, ping, N);
  }
  // it9 wrote ping
  lsm_k<<<gblocks, 256, 0, stream>>>(ping, d_out, flags, N);
}